// Round 5
// baseline (1654.124 us; speedup 1.0000x reference)
//
#include <hip/hip_runtime.h>
#include <hip/hip_bf16.h>
#include <math.h>

#define EPSV 1e-5f
typedef unsigned long long u64;
typedef unsigned short u16;

__device__ __forceinline__ float bnf(float x, float g, float c, float m, float v) {
    return g * (x - m) * rsqrtf(v + EPSV) + c;
}

// =================== conv1 prep: pad input, transpose-pack signed weights ===================

__global__ __launch_bounds__(256) void pad_x(const float* __restrict__ x,
                                             float* __restrict__ Xp) {
    int idx = blockIdx.x * 256 + threadIdx.x;
    const int total = 128 * 3 * 228 * 228;
    if (idx >= total) return;
    int iwp = idx % 228;
    int t = idx / 228;
    int ihp = t % 228;
    int nc = t / 228;
    int iw = iwp - 2, ih = ihp - 2;
    float v = 0.f;
    if ((unsigned)iw < 224u && (unsigned)ih < 224u)
        v = x[((size_t)nc * 224 + ih) * 224 + iw];
    Xp[idx] = v;
}

// W1 [96,3,11,11] -> Wp [6 cog][3 ci][11 kh][11 kw][16 co] as +-1 fp32
__global__ __launch_bounds__(256) void pack_w1t(const float* __restrict__ W,
                                                float* __restrict__ Wp) {
    int idx = blockIdx.x * 256 + threadIdx.x;
    const int total = 6 * 3 * 11 * 11 * 16;
    if (idx >= total) return;
    int j = idx % 16;
    int t = idx / 16;
    int kw = t % 11; t /= 11;
    int kh = t % 11; t /= 11;
    int ci = t % 3;
    int cog = t / 3;
    int co = cog * 16 + j;
    float w = W[(((size_t)co * 3 + ci) * 11 + kh) * 11 + kw];
    Wp[idx] = (w > 0.f) ? 1.f : -1.f;
}

// =================== conv1: pixel-linearized, 16 co/block -> u16 sign masks ===================
// grid (128 n, 12 pchunk, 6 cog), block 256 = 4 waves; thread -> pixel p = oh*55+ow
// (linearized: 48 waves per (n,cog) instead of 56 -> no per-row lane padding)
// S1b: u16 [n][55][55][8] (cog 0..5 used)
__global__ __launch_bounds__(256) void conv1_tile(
    const float* __restrict__ Xp, const float* __restrict__ Wp,
    const float* __restrict__ bias, u16* __restrict__ S1b) {
    const int Hp = 228, Wpad = 228, OH = 55, OW = 55;
    int n = blockIdx.x, cog = blockIdx.z;
    int p = blockIdx.y * 256 + threadIdx.x;
    bool act = p < OH * OW;
    int pc = act ? p : (OH * OW - 1);
    int oh = pc / OW;
    int ow = pc - oh * OW;

    float acc[16];
    #pragma unroll
    for (int j = 0; j < 16; ++j) acc[j] = 0.f;

    const float* __restrict__ wbase = Wp + (size_t)cog * (3 * 11 * 11 * 16);

    for (int ci = 0; ci < 3; ++ci) {
        const float* xrow0 = Xp + ((size_t)(n * 3 + ci) * Hp + oh * 4) * Wpad + ow * 4;
        const float* __restrict__ wci = wbase + ci * (11 * 11 * 16);
        for (int kh = 0; kh < 11; ++kh) {
            const float4* xr = (const float4*)(xrow0 + kh * Wpad);
            float4 a = xr[0], b = xr[1], c = xr[2];
            float xv[12] = {a.x, a.y, a.z, a.w, b.x, b.y, b.z, b.w, c.x, c.y, c.z, c.w};
            const float* __restrict__ wk = wci + kh * (11 * 16);
            #pragma unroll
            for (int kw = 0; kw < 11; ++kw) {
                #pragma unroll
                for (int j = 0; j < 16; ++j)
                    acc[j] += wk[kw * 16 + j] * xv[kw];
            }
        }
    }

    if (act) {
        unsigned mask = 0;
        #pragma unroll
        for (int j = 0; j < 16; ++j)
            mask |= (acc[j] + bias[cog * 16 + j] > 0.f) ? (1u << j) : 0u;
        S1b[((size_t)(n * OH + oh) * OW + ow) * 8 + cog] = (u16)mask;
    }
}

// =================== pool1 + bn1 + sign: pure bitwise ===================
// grid = 128*27 (n, oh'), block 256, tid -> (ow' 0..26, cog 0..7)
// P1 u16-view: [n][27][27][8] == u64 [pixel][2]
__global__ __launch_bounds__(256) void pool1_bit(
    const u16* __restrict__ S1b,
    const float* __restrict__ g, const float* __restrict__ cb,
    const float* __restrict__ m, const float* __restrict__ v,
    u16* __restrict__ P1) {
    int n = blockIdx.x / 27;
    int ohp = blockIdx.x % 27;
    int tid = threadIdx.x;
    if (tid >= 216) return;
    int cog = tid & 7;
    int owp = tid >> 3;
    unsigned res = 0;
    if (cog < 6) {
        unsigned tp = 0, tn = 0;
        #pragma unroll
        for (int j = 0; j < 16; ++j) {
            int c = cog * 16 + j;
            float gg = g[c], cc = cb[c], mm = m[c], vv = v[c];
            tp |= (bnf(1.f, gg, cc, mm, vv) > 0.f) ? (1u << j) : 0u;
            tn |= (bnf(-1.f, gg, cc, mm, vv) > 0.f) ? (1u << j) : 0u;
        }
        unsigned mk = 0;
        #pragma unroll
        for (int kh = 0; kh < 3; ++kh)
            #pragma unroll
            for (int kw = 0; kw < 3; ++kw)
                mk |= S1b[((size_t)(n * 55 + 2 * ohp + kh) * 55 + 2 * owp + kw) * 8 + cog];
        res = (mk & tp) | (~mk & tn & 0xffffu);
    }
    P1[((size_t)(n * 27 + ohp) * 27 + owp) * 8 + cog] = (u16)res;
}

// =================== weight packs: conv (transposed), fc ===================

// OIHW -> wT u64 [kh][kw][cw][Co]
template <int K, int CW>
__global__ __launch_bounds__(256) void pack_wc_t(const float* __restrict__ W,
                                                 u64* __restrict__ out, int Ci, int Co) {
    int wid = blockIdx.x * 4 + (threadIdx.x >> 6);
    int b = threadIdx.x & 63;
    int total = Co * K * K * CW;
    if (wid >= total) return;
    int cw = wid % CW;
    int t = wid / CW;
    int kw = t % K; t /= K;
    int kh = t % K;
    int co = t / K;
    int ci = cw * 64 + b;
    int bit = 0;
    if (ci < Ci) bit = W[(((size_t)co * Ci + ci) * K + kh) * K + kw] > 0.f;
    u64 mask = __ballot(bit);
    if (b == 0) out[(size_t)(((kh * K + kw) * CW + cw)) * Co + co] = mask;
}

// fc6 [4096, 9216] (col = c*36+p) -> wgtT [144][4096]; coalesced read + LDS transpose
__global__ __launch_bounds__(256) void pack_wfc6_t(const float* __restrict__ W,
                                                   u64* __restrict__ out) {
    __shared__ float lds[256 * 37];
    int o = blockIdx.x;
    int tid = threadIdx.x;
    for (int i = tid; i < 9216; i += 256) {
        int c = i / 36, p = i - c * 36;
        lds[c * 37 + p] = W[(size_t)o * 9216 + i];
    }
    __syncthreads();
    int wave = tid >> 6, lane = tid & 63;
    for (int jj = wave; jj < 144; jj += 4) {
        int p = jj >> 2, cw = jj & 3;
        int bit = lds[(cw * 64 + lane) * 37 + p] > 0.f;
        u64 mask = __ballot(bit);
        if (lane == 0) out[(size_t)jj * 4096 + o] = mask;
    }
}

// fc7/fc8 [O, 4096] -> transposed [64][O] (reads coalesced: lane=b consecutive)
__global__ __launch_bounds__(256) void pack_wfc(const float* __restrict__ W,
                                                u64* __restrict__ out, int O) {
    int wid = blockIdx.x * 4 + (threadIdx.x >> 6);  // wid = o*64 + j
    int b = threadIdx.x & 63;
    if (wid >= O * 64) return;
    int o = wid >> 6;
    int j = wid & 63;
    float val = W[(size_t)o * 4096 + j * 64 + b];
    u64 mask = __ballot(val > 0.f);
    if (b == 0) out[(size_t)j * O + o] = mask;
}

// =================== binary conv: co-as-lane, weights in VGPR, act uniform ===================
// act u64 [n][H][W][CW]; wT u64 [kh][kw][cw][CO]
// BNPACK=false: out fp32 NHWC [n][H][W][CO]
// BNPACK=true : bn+sign fused, pout u64 [n][HW][CO/64] (lane=co -> ballot pack)
template <int K, int P, int CW, int HW, int W, int CO, int PIX, int CI, bool BNPACK>
__global__ __launch_bounds__(CO) void bconv_co(
    const u64* __restrict__ act, const u64* __restrict__ wT,
    const float* __restrict__ bias, float* __restrict__ out,
    const float* __restrict__ g, const float* __restrict__ cb,
    const float* __restrict__ m, const float* __restrict__ v,
    u64* __restrict__ pout) {
    const int H = HW / W;
    int co = threadIdx.x;
    int n = blockIdx.y;
    int p0 = blockIdx.x * PIX;
    u64 wreg[K * K * CW];
    #pragma unroll
    for (int t = 0; t < K * K * CW; ++t) wreg[t] = wT[(size_t)t * CO + co];
    float b = bias[co];
    float gg = 0.f, ccv = 0.f, mmv = 0.f, vvv = 0.f;
    if constexpr (BNPACK) {
        gg = g[co]; ccv = cb[co]; mmv = m[co]; vvv = v[co];
    }
    #pragma unroll
    for (int p = 0; p < PIX; ++p) {
        int pix = p0 + p;
        if (pix >= HW) break;
        int oh = pix / W, ow = pix - oh * W;
        int mism = 0, nval = 0;
        #pragma unroll
        for (int kh = 0; kh < K; ++kh) {
            int ih = oh - P + kh;
            if ((unsigned)ih >= (unsigned)H) continue;
            #pragma unroll
            for (int kw = 0; kw < K; ++kw) {
                int iw = ow - P + kw;
                if ((unsigned)iw >= (unsigned)W) continue;
                const u64* ap = act + ((size_t)(n * H + ih) * W + iw) * CW;
                #pragma unroll
                for (int cw = 0; cw < CW; ++cw)
                    mism += __popcll(ap[cw] ^ wreg[(kh * K + kw) * CW + cw]);
                nval++;
            }
        }
        float val = (float)(nval * CI - 2 * mism) + b;
        if constexpr (BNPACK) {
            float y = bnf(val, gg, ccv, mmv, vvv);
            u64 msk = __ballot(y > 0.f);
            if ((co & 63) == 0)
                pout[((size_t)n * HW + pix) * (CO >> 6) + (co >> 6)] = msk;
        } else {
            out[((size_t)n * HW + pix) * CO + co] = val;
        }
    }
}

// =================== bitwise 3x3 s2 max-pool of sign(bn(x)) masks ===================
// S [n][H][W][CW] u64 = per-pixel sign(bn(val)) bits (from BNPACK epilogue).
// bnf monotone in val: g>0 -> pooled bit = OR over window; g<0 -> AND. Exact.
// (g==0: bnf constant in val -> all window bits equal -> orv==andv, either ok.)
// block = CW*64 threads (c = tid), grid = n*OH*OW
__global__ __launch_bounds__(256) void pool_bit(
    const u64* __restrict__ S, const float* __restrict__ g,
    u64* __restrict__ P, int H, int W, int OH, int OW, int CW) {
    int bx = blockIdx.x;
    int ow = bx % OW;
    int t = bx / OW;
    int oh = t % OH;
    int n = t / OH;
    int c = threadIdx.x;
    int w = c >> 6, b = c & 63;
    u64 orv = 0, andv = ~0ull;
    #pragma unroll
    for (int kh = 0; kh < 3; ++kh)
        #pragma unroll
        for (int kw = 0; kw < 3; ++kw) {
            u64 mk = S[((size_t)(n * H + oh * 2 + kh) * W + ow * 2 + kw) * CW + w];
            orv |= mk;
            andv &= mk;
        }
    u64 sel = (g[c] > 0.f) ? orv : andv;
    int bit = (int)((sel >> b) & 1ull);
    u64 mask = __ballot(bit);
    if ((c & 63) == 0) P[(size_t)bx * CW + w] = mask;
}

// =================== binary FC via xnor-popcount (plain fp32 out) ===================
__global__ __launch_bounds__(256) void fc_bit(
    const u64* __restrict__ actw, const u64* __restrict__ wgtT,
    const float* __restrict__ bias, float* __restrict__ out, int IW, int O) {
    int o = blockIdx.x * 256 + threadIdx.x;
    if (o >= O) return;
    int n0 = blockIdx.y * 8;
    const u64* ap = actw + (size_t)n0 * IW;
    int acc[8];
    #pragma unroll
    for (int r = 0; r < 8; ++r) acc[r] = 0;
    for (int w = 0; w < IW; ++w) {
        u64 wv = wgtT[(size_t)w * O + o];
        #pragma unroll
        for (int r = 0; r < 8; ++r)
            acc[r] += __popcll(ap[(size_t)r * IW + w] ^ wv);
    }
    float b = bias[o];
    #pragma unroll
    for (int r = 0; r < 8; ++r)
        out[(size_t)(n0 + r) * O + o] = (float)(IW * 64 - 2 * acc[r]) + b;
}

// =================== binary FC + bn + sign -> packed (o == lane -> ballot) ===================
// requires O % 256 == 0; out u64 [n][O/64]
__global__ __launch_bounds__(256) void fc_bit_bnpack(
    const u64* __restrict__ actw, const u64* __restrict__ wgtT,
    const float* __restrict__ bias,
    const float* __restrict__ g, const float* __restrict__ cb,
    const float* __restrict__ m, const float* __restrict__ v,
    u64* __restrict__ out, int IW, int O) {
    int o = blockIdx.x * 256 + threadIdx.x;
    int n0 = blockIdx.y * 8;
    const u64* ap = actw + (size_t)n0 * IW;
    int acc[8];
    #pragma unroll
    for (int r = 0; r < 8; ++r) acc[r] = 0;
    for (int w = 0; w < IW; ++w) {
        u64 wv = wgtT[(size_t)w * O + o];
        #pragma unroll
        for (int r = 0; r < 8; ++r)
            acc[r] += __popcll(ap[(size_t)r * IW + w] ^ wv);
    }
    float b = bias[o];
    float gg = g[o], ccv = cb[o], mmv = m[o], vvv = v[o];
    int ow = O >> 6;
    #pragma unroll
    for (int r = 0; r < 8; ++r) {
        float val = (float)(IW * 64 - 2 * acc[r]) + b;
        float y = bnf(val, gg, ccv, mmv, vvv);
        u64 msk = __ballot(y > 0.f);
        if ((threadIdx.x & 63) == 0)
            out[(size_t)(n0 + r) * ow + (o >> 6)] = msk;
    }
}

// =================== BN8 + log_softmax, one block per batch row ===================
__global__ __launch_bounds__(256) void bn_lsm_kernel(
    const float* __restrict__ in,
    const float* __restrict__ g, const float* __restrict__ cb,
    const float* __restrict__ m, const float* __restrict__ v,
    float* __restrict__ out, int O) {
    int n = blockIdx.x;
    __shared__ float buf[1000];
    __shared__ float red[256];
    int tid = threadIdx.x;
    float lmax = -INFINITY;
    for (int o = tid; o < O; o += 256) {
        float y = bnf(in[(size_t)n * O + o], g[o], cb[o], m[o], v[o]);
        buf[o] = y;
        lmax = fmaxf(lmax, y);
    }
    red[tid] = lmax;
    __syncthreads();
    for (int s = 128; s > 0; s >>= 1) {
        if (tid < s) red[tid] = fmaxf(red[tid], red[tid + s]);
        __syncthreads();
    }
    float mx = red[0];
    __syncthreads();
    float lsum = 0.f;
    for (int o = tid; o < O; o += 256) lsum += expf(buf[o] - mx);
    red[tid] = lsum;
    __syncthreads();
    for (int s = 128; s > 0; s >>= 1) {
        if (tid < s) red[tid] += red[tid + s];
        __syncthreads();
    }
    float lse = mx + logf(red[0]);
    for (int o = tid; o < O; o += 256) out[(size_t)n * O + o] = buf[o] - lse;
}

extern "C" void kernel_launch(void* const* d_in, const int* in_sizes, int n_in,
                              void* d_out, int out_size, void* d_ws, size_t ws_size,
                              hipStream_t stream) {
    const float* x = (const float*)d_in[0];
    auto L = [&](int layer, int k) -> const float* {
        return (const float*)d_in[1 + (layer - 1) * 6 + k];
    };

    char* ws = (char*)d_ws;
    float* A   = (float*)(ws + 0);           // fp32 scratch: Xp (79.8MB), later fc outs (2MB)
    float* Xp  = A;                          // padded input aliases A (79,847,424 B)
    u64* S2b   = (u64*)(ws + 79847424);      // [128,729,4] conv2 sign bits  2,985,984
    u64* S5b   = (u64*)(ws + 82833408);      // [128,169,4] conv5 sign bits    692,224
    u16* S1b   = (u16*)(ws + 95551488);      // [128,55,55,8] u16     6,195,200
    u16* P1u   = (u16*)(ws + 101746688);     // [128,27,27,8] u16     1,492,992
    u64* P1    = (u64*)P1u;
    u64* P2    = (u64*)(ws + 103239680);     // [128,13,13,4]           692,224
    u64* P3a   = (u64*)(ws + 103931904);     // [128,13,13,6]         1,038,336
    u64* P3b   = (u64*)(ws + 104970240);     // [128,13,13,6]         1,038,336
    u64* P5    = (u64*)(ws + 106008576);     // [128,36,4]              147,456
    u64* F7    = (u64*)(ws + 106156032);     // [128,64]                 65,536
    u64* F8    = (u64*)(ws + 106221568);     // [128,64]                 65,536
    u64* WcT2  = (u64*)(ws + 106287104);     // [5,5,2,256]             102,400
    u64* WcT3  = (u64*)(ws + 106389504);     // [3,3,4,384]             110,592
    u64* WcT4  = (u64*)(ws + 106500096);     // [3,3,6,384]             165,888
    u64* WcT5  = (u64*)(ws + 106665984);     // [3,3,6,256]             110,592
    u64* Wf6   = (u64*)(ws + 106776576);     // [144,4096]            4,718,592
    u64* Wf7   = (u64*)(ws + 111495168);     // [64,4096]             2,097,152
    u64* Wf8   = (u64*)(ws + 113592320);     // [64,1000]               512,000
    float* Wp1 = (float*)(ws + 114104320);   // [6,3,11,11,16]          139,392

    // ---- weight packs / input pad ----
    pack_w1t<<<137, 256, 0, stream>>>(L(1, 0), Wp1);
    pad_x<<<(128 * 3 * 228 * 228 + 255) / 256, 256, 0, stream>>>(x, Xp);
    pack_wc_t<5, 2><<<3200, 256, 0, stream>>>(L(2, 0), WcT2, 96, 256);
    pack_wc_t<3, 4><<<3456, 256, 0, stream>>>(L(3, 0), WcT3, 256, 384);
    pack_wc_t<3, 6><<<5184, 256, 0, stream>>>(L(4, 0), WcT4, 384, 384);
    pack_wc_t<3, 6><<<3456, 256, 0, stream>>>(L(5, 0), WcT5, 384, 256);
    pack_wfc6_t<<<4096, 256, 0, stream>>>(L(6, 0), Wf6);
    pack_wfc<<<65536, 256, 0, stream>>>(L(7, 0), Wf7, 4096);
    pack_wfc<<<16000, 256, 0, stream>>>(L(8, 0), Wf8, 1000);

    // ---- network ----
    // conv1 -> S1b u16 sign masks (pixel-linearized: 12 chunks of 256 pixels)
    {
        dim3 g(128, 12, 6);
        conv1_tile<<<g, 256, 0, stream>>>(Xp, Wp1, L(1, 1), S1b);
    }
    // pool1 + bn1 + sign (bitwise) -> P1 [128,27,27,2 u64]
    pool1_bit<<<128 * 27, 256, 0, stream>>>(S1b, L(1, 2), L(1, 3), L(1, 4), L(1, 5), P1u);
    // conv2 (K5,P2) + bn2 + sign -> S2b bits [128,729,4] (pool follows in bit domain)
    {
        dim3 g((729 + 7) / 8, 128);
        bconv_co<5, 2, 2, 729, 27, 256, 8, 96, true><<<g, 256, 0, stream>>>(
            P1, WcT2, L(2, 1), nullptr, L(2, 2), L(2, 3), L(2, 4), L(2, 5), S2b);
    }
    // pool2 (bitwise OR/AND by sign(g2)) -> P2 [128,169,4]
    pool_bit<<<128 * 13 * 13, 256, 0, stream>>>(S2b, L(2, 2), P2, 27, 27, 13, 13, 4);
    // conv3 + bn3 + sign -> P3a (fused, packed out)
    {
        dim3 g((169 + 3) / 4, 128);
        bconv_co<3, 1, 4, 169, 13, 384, 4, 256, true><<<g, 384, 0, stream>>>(
            P2, WcT3, L(3, 1), nullptr, L(3, 2), L(3, 3), L(3, 4), L(3, 5), P3a);
    }
    // conv4 + bn4 + sign -> P3b (fused, packed out)
    {
        dim3 g((169 + 3) / 4, 128);
        bconv_co<3, 1, 6, 169, 13, 384, 4, 384, true><<<g, 384, 0, stream>>>(
            P3a, WcT4, L(4, 1), nullptr, L(4, 2), L(4, 3), L(4, 4), L(4, 5), P3b);
    }
    // conv5 + bn5 + sign -> S5b bits [128,169,4] (pool follows in bit domain)
    {
        dim3 g((169 + 3) / 4, 128);
        bconv_co<3, 1, 6, 169, 13, 256, 4, 384, true><<<g, 256, 0, stream>>>(
            P3b, WcT5, L(5, 1), nullptr, L(5, 2), L(5, 3), L(5, 4), L(5, 5), S5b);
    }
    // pool5 (bitwise) -> P5 [128,36,4] (fc6 input)
    pool_bit<<<128 * 6 * 6, 256, 0, stream>>>(S5b, L(5, 2), P5, 13, 13, 6, 6, 4);
    // fc6 + bn6 + sign -> F7 (fused)
    {
        dim3 g(16, 16);
        fc_bit_bnpack<<<g, 256, 0, stream>>>(P5, Wf6, L(6, 1),
                                             L(6, 2), L(6, 3), L(6, 4), L(6, 5), F7, 144, 4096);
    }
    // fc7 + bn7 + sign -> F8 (fused)
    {
        dim3 g(16, 16);
        fc_bit_bnpack<<<g, 256, 0, stream>>>(F7, Wf7, L(7, 1),
                                             L(7, 2), L(7, 3), L(7, 4), L(7, 5), F8, 64, 4096);
    }
    // fc8 -> A [128,1000]
    {
        dim3 g(4, 16);
        fc_bit<<<g, 256, 0, stream>>>(F8, Wf8, L(8, 1), A, 64, 1000);
    }
    // bn8 + log_softmax -> d_out
    bn_lsm_kernel<<<128, 256, 0, stream>>>(A, L(8, 2), L(8, 3), L(8, 4), L(8, 5),
                                           (float*)d_out, 1000);
}